// Round 5
// baseline (356.443 us; speedup 1.0000x reference)
//
#include <hip/hip_runtime.h>

#define NEG_SLOPE 0.01f
#define EPB 4096          // edges per block in bucket build
#define NB_SHIFT 8        // 256 dst-nodes per bucket

typedef __attribute__((ext_vector_type(8))) short bf16x8;
typedef __attribute__((ext_vector_type(4))) float floatx4;

__device__ __forceinline__ short f2bf(float f) {
    union { float f; unsigned u; } v; v.f = f;
    unsigned u = v.u;
    u += 0x7FFF + ((u >> 16) & 1);          // round-to-nearest-even
    return (short)(u >> 16);
}
__device__ __forceinline__ float bf2f(short s) {
    union { unsigned u; float f; } v;
    v.u = ((unsigned)(unsigned short)s) << 16;
    return v.f;
}

// ---------------- degree / row_ptr ----------------

__global__ void init_counts(int* counts, int n) {
    int i = blockIdx.x * blockDim.x + threadIdx.x;
    if (i < n) counts[i] = 0;
}

__global__ void count_edges(const int* __restrict__ dst, int* counts, int E) {
    int e = blockIdx.x * blockDim.x + threadIdx.x;
    if (e < E) atomicAdd(&counts[dst[e]], 1);
}

// per-1024-block exclusive scan; blockSums[b] = block total
__global__ void scan_blocks(const int* __restrict__ counts, int* row_ptr,
                            int* blockSums, int n) {
    int tid = threadIdx.x;
    int gid = blockIdx.x * 1024 + tid;
    int v = (gid < n) ? counts[gid] : 0;
    int lane = tid & 63, wave = tid >> 6;
    __shared__ int waveSums[16];
    __shared__ int waveOff[16];
    int s = v;
    #pragma unroll
    for (int off = 1; off < 64; off <<= 1) {
        int t = __shfl_up(s, off);
        if (lane >= off) s += t;
    }
    if (lane == 63) waveSums[wave] = s;
    __syncthreads();
    if (tid == 0) {
        int acc = 0;
        for (int w = 0; w < 16; w++) { waveOff[w] = acc; acc += waveSums[w]; }
        blockSums[blockIdx.x] = acc;
    }
    __syncthreads();
    if (gid < n) row_ptr[gid] = s - v + waveOff[wave];
}

__global__ void scan_sums(int* blockSums, int nb) {
    if (threadIdx.x == 0 && blockIdx.x == 0) {
        int acc = 0;
        for (int b = 0; b < nb; b++) { int t = blockSums[b]; blockSums[b] = acc; acc += t; }
    }
}

// row_ptr += blockSums[bid]; dis = rsqrt(1+count); row_end = row_ptr + count
__global__ void finalize_scan(int* row_ptr, const int* __restrict__ blockSums,
                              int* counts_to_rowend, float* dis, int n) {
    int gid = blockIdx.x * 1024 + threadIdx.x;
    if (gid < n) {
        int c = counts_to_rowend[gid];                 // original count
        dis[gid] = rsqrtf(1.0f + (float)c);            // self-loop folded into degree
        int rp = row_ptr[gid] + blockSums[blockIdx.x];
        row_ptr[gid] = rp;
        counts_to_rowend[gid] = rp + c;                // becomes row_end
    }
}

// ---------------- bucketed CSR build (XCD-local, coalesced writes) ----------------
// Bucket k holds dst in [k*256, (k+1)*256). hist layout bucket-major: hist[k*B + b].

__global__ void bucket_hist(const int* __restrict__ dst, int E, int B, int K,
                            int* __restrict__ hist) {
    __shared__ int lh[1024];
    int b = blockIdx.x;
    for (int i = threadIdx.x; i < K; i += 256) lh[i] = 0;
    __syncthreads();
    int lo = b * EPB, hi = min(lo + EPB, E);
    for (int e = lo + threadIdx.x; e < hi; e += 256)
        atomicAdd(&lh[dst[e] >> NB_SHIFT], 1);
    __syncthreads();
    for (int i = threadIdx.x; i < K; i += 256)
        hist[i * B + b] = lh[i];
}

// single-block exclusive scan of hist[M], in place
__global__ void scan_hist(int* hist, int M) {
    __shared__ int waveTot[16];
    __shared__ int waveOff[16];
    int tid = threadIdx.x;                 // 1024 threads
    int chunk = (M + 1023) / 1024;
    int lo = tid * chunk, hi = min(lo + chunk, M);
    int sum = 0;
    for (int i = lo; i < hi; i++) sum += hist[i];
    int lane = tid & 63, wave = tid >> 6;
    int s = sum;
    #pragma unroll
    for (int o = 1; o < 64; o <<= 1) {
        int t = __shfl_up(s, o);
        if (lane >= o) s += t;
    }
    if (lane == 63) waveTot[wave] = s;
    __syncthreads();
    if (tid == 0) {
        int acc = 0;
        for (int w = 0; w < 16; w++) { waveOff[w] = acc; acc += waveTot[w]; }
    }
    __syncthreads();
    int run = s - sum + waveOff[wave];     // exclusive offset of this thread's chunk
    for (int i = lo; i < hi; i++) { int v = hist[i]; hist[i] = run; run += v; }
}

__global__ void bucket_scatter(const int* __restrict__ src, const int* __restrict__ dst,
                               int E, int B, int K, const int* __restrict__ scanned,
                               int2* __restrict__ bucketed) {
    __shared__ int lcur[1024];
    int b = blockIdx.x;
    for (int i = threadIdx.x; i < K; i += 256) lcur[i] = scanned[i * B + b];
    __syncthreads();
    int lo = b * EPB, hi = min(lo + EPB, E);
    for (int e = lo + threadIdx.x; e < hi; e += 256) {
        int d = dst[e], sv = src[e];
        int pos = atomicAdd(&lcur[d >> NB_SHIFT], 1);
        bucketed[pos] = make_int2(sv, d);
    }
}

// one block per bucket: all CSR writes for this dst-range come from one block
__global__ void fill_csr_bucketed(const int2* __restrict__ bucketed,
                                  const int* __restrict__ scanned, int B, int K, int E,
                                  const int* __restrict__ row_ptr,
                                  int* __restrict__ csr_src, int N) {
    __shared__ int lcur[256];
    int k = blockIdx.x;
    int base = k << NB_SHIFT;
    {
        int node = base + threadIdx.x;
        lcur[threadIdx.x] = (node < N) ? row_ptr[node] : 0;
    }
    __syncthreads();
    int lo = scanned[k * B];
    int hi = (k + 1 < K) ? scanned[(k + 1) * B] : E;
    for (int e = lo + threadIdx.x; e < hi; e += 256) {
        int2 sd = bucketed[e];
        int pos = atomicAdd(&lcur[sd.y - base], 1);
        csr_src[pos] = sd.x;
    }
}

// ---------------- weight pack: fp32 [K][N] -> bf16 transposed [N][K] ----------------

__global__ void pack_w1t(const float* __restrict__ W1, short* __restrict__ W1t) {
    int i = blockIdx.x * blockDim.x + threadIdx.x;   // i = n*256 + k, n<128, k<256
    if (i < 128 * 256) {
        int n = i >> 8, k = i & 255;
        W1t[i] = f2bf(W1[k * 128 + n]);
    }
}

__global__ void pack_wcat_t(const float* __restrict__ Wmu, const float* __restrict__ Wlv,
                            short* __restrict__ Wt) {
    int i = blockIdx.x * blockDim.x + threadIdx.x;   // i = n*128 + k, n<128, k<128
    if (i < 128 * 128) {
        int n = i >> 7, k = i & 127;
        float v = (n < 64) ? Wmu[k * 64 + n] : Wlv[k * 64 + (n - 64)];
        Wt[i] = f2bf(v);
    }
}

// ---------------- MFMA GEMM: C[M,128](bf16) = A[M,K] @ W (bf16 Wt[128][K]) ----------------
// No LDS: N-tile = full 128 cols. Block 256 thr = 4 waves; wave w: rows blk*64+w*16..+15.
// A frag (16x16x32): lane holds A[m=lane&15][k0+(lane>>4)*8+j]; fp32 A converts, bf16 A loads direct.
// B frag: lane holds Wt[n=lane&15 + t*16][k0+q*8+j] -> contiguous 16B bf16 load.
// C/D: col=lane&15, row=(lane>>4)*4+reg (m89-verified). Epilogue: row scale by dis[row], cvt bf16.

template<bool ABF16>
__launch_bounds__(256)
__global__ void gemm_mfma(const void* __restrict__ Ap, const short* __restrict__ Wt,
                          short* __restrict__ C, int M, int K,
                          const float* __restrict__ dis) {
    int w = threadIdx.x >> 6;
    int lane = threadIdx.x & 63;
    int ln = lane & 15;
    int q  = lane >> 4;
    int rowTile = blockIdx.x * 64 + w * 16;

    int rowA = rowTile + ln;
    if (rowA >= M) rowA = M - 1;                 // clamp; stores are guarded
    const short* bBase = Wt + q * 8;

    floatx4 acc[8];
    #pragma unroll
    for (int t = 0; t < 8; t++) acc[t] = (floatx4){0.f, 0.f, 0.f, 0.f};

    const float* aRowF = (const float*)Ap + (size_t)rowA * K + q * 8;
    const short* aRowB = (const short*)Ap + (size_t)rowA * K + q * 8;

    for (int kt = 0; kt < K; kt += 32) {
        bf16x8 aF;
        if (ABF16) {
            aF = *(const bf16x8*)(aRowB + kt);
        } else {
            float4 af0 = *(const float4*)(aRowF + kt);
            float4 af1 = *(const float4*)(aRowF + kt + 4);
            aF[0] = f2bf(af0.x); aF[1] = f2bf(af0.y); aF[2] = f2bf(af0.z); aF[3] = f2bf(af0.w);
            aF[4] = f2bf(af1.x); aF[5] = f2bf(af1.y); aF[6] = f2bf(af1.z); aF[7] = f2bf(af1.w);
        }
        bf16x8 bF[8];
        #pragma unroll
        for (int t = 0; t < 8; t++)
            bF[t] = *(const bf16x8*)(bBase + (size_t)(t * 16 + ln) * K + kt);
        #pragma unroll
        for (int t = 0; t < 8; t++)
            acc[t] = __builtin_amdgcn_mfma_f32_16x16x32_bf16(aF, bF[t], acc[t], 0, 0, 0);
    }

    #pragma unroll
    for (int reg = 0; reg < 4; reg++) {
        int r = rowTile + q * 4 + reg;
        if (r < M) {
            float s = dis ? dis[r] : 1.f;
            #pragma unroll
            for (int t = 0; t < 8; t++)
                C[(size_t)r * 128 + t * 16 + ln] = f2bf(s * acc[t][reg]);
        }
    }
}

// ---------------- aggregation: one WAVE per node, bf16 rows, quarter-wave gathers ----------------
// zp holds pre-scaled bf16 rows z'[i] = dis[i] * (transform(x))[i]  (128 feats = 256B).
// out_node = dis[d] * ( sum_{s in N(d)} z'[s] + z'[d] ) + bias

#define AGG_BODY_BF16                                                         \
    int wave = threadIdx.x >> 6;                                              \
    int node = blockIdx.x * 4 + wave;                                         \
    if (node >= N) return;                                                    \
    int lane = threadIdx.x & 63;                                              \
    int qi = lane >> 4;                                                       \
    int fl = lane & 15;                                                       \
    int fo = fl * 8;                                                          \
    const short* zb = zp + fo;                                                \
    int start = row_ptr[node], end = row_end[node];                           \
    float acc[8];                                                             \
    _Pragma("unroll")                                                         \
    for (int j = 0; j < 8; j++) acc[j] = 0.f;                                 \
    int e = start + qi;                                                       \
    for (; e + 4 < end; e += 8) {                                             \
        int s0 = csr_src[e], s1 = csr_src[e + 4];                             \
        bf16x8 z0 = *(const bf16x8*)(zb + (size_t)s0 * 128);                  \
        bf16x8 z1 = *(const bf16x8*)(zb + (size_t)s1 * 128);                  \
        _Pragma("unroll")                                                     \
        for (int j = 0; j < 8; j++) acc[j] += bf2f(z0[j]) + bf2f(z1[j]);      \
    }                                                                         \
    for (; e < end; e += 4) {                                                 \
        int s0 = csr_src[e];                                                  \
        bf16x8 z0 = *(const bf16x8*)(zb + (size_t)s0 * 128);                  \
        _Pragma("unroll")                                                     \
        for (int j = 0; j < 8; j++) acc[j] += bf2f(z0[j]);                    \
    }                                                                         \
    if (qi == 0) {  /* self loop, added exactly once */                       \
        bf16x8 zs = *(const bf16x8*)(zb + (size_t)node * 128);                \
        _Pragma("unroll")                                                     \
        for (int j = 0; j < 8; j++) acc[j] += bf2f(zs[j]);                    \
    }                                                                         \
    _Pragma("unroll")                                                         \
    for (int j = 0; j < 8; j++) {                                             \
        acc[j] += __shfl_xor(acc[j], 16);                                     \
        acc[j] += __shfl_xor(acc[j], 32);                                     \
    }

__launch_bounds__(256)
__global__ void agg_layer1(const short* __restrict__ zp, const int* __restrict__ row_ptr,
                           const int* __restrict__ row_end, const int* __restrict__ csr_src,
                           const float* __restrict__ dis, const float* __restrict__ b1,
                           short* __restrict__ h, int N) {
    AGG_BODY_BF16
    if (qi == 0) {
        float d = dis[node];
        bf16x8 ov;
        #pragma unroll
        for (int j = 0; j < 8; j++) {
            float v = fmaf(d, acc[j], b1[fo + j]);
            v = (v > 0.f) ? v : NEG_SLOPE * v;
            ov[j] = f2bf(v);
        }
        *(bf16x8*)(h + (size_t)node * 128 + fo) = ov;
    }
}

__launch_bounds__(256)
__global__ void agg_layer2(const short* __restrict__ zp, const int* __restrict__ row_ptr,
                           const int* __restrict__ row_end, const int* __restrict__ csr_src,
                           const float* __restrict__ dis, const float* __restrict__ b_mu,
                           const float* __restrict__ b_lv, float* __restrict__ out, int N) {
    AGG_BODY_BF16
    if (qi == 0) {
        float d = dis[node];
        float r[8];
        if (fl < 8) {                        // mu: features fo..fo+7
            #pragma unroll
            for (int j = 0; j < 8; j++) r[j] = fmaf(d, acc[j], b_mu[fo + j]);
            float* p = out + (size_t)node * 64 + fo;
            *(float4*)p       = make_float4(r[0], r[1], r[2], r[3]);
            *(float4*)(p + 4) = make_float4(r[4], r[5], r[6], r[7]);
        } else {                             // logvar: features fo-64..fo-57
            #pragma unroll
            for (int j = 0; j < 8; j++) r[j] = fmaf(d, acc[j], b_lv[fo - 64 + j]);
            float* p = out + (size_t)N * 64 + (size_t)node * 64 + (fo - 64);
            *(float4*)p       = make_float4(r[0], r[1], r[2], r[3]);
            *(float4*)(p + 4) = make_float4(r[4], r[5], r[6], r[7]);
        }
    }
}

// ---------------- launcher ----------------

extern "C" void kernel_launch(void* const* d_in, const int* in_sizes, int n_in,
                              void* d_out, int out_size, void* d_ws, size_t ws_size,
                              hipStream_t stream) {
    const float* x   = (const float*)d_in[0];
    const int*   ei  = (const int*)d_in[1];    // [2,E] int32: src then dst
    const float* W1  = (const float*)d_in[2];
    const float* b1  = (const float*)d_in[3];
    const float* Wmu = (const float*)d_in[4];
    const float* bmu = (const float*)d_in[5];
    const float* Wlv = (const float*)d_in[6];
    const float* blv = (const float*)d_in[7];
    float* out = (float*)d_out;

    const int F_IN = 256;
    int N = in_sizes[0] / F_IN;   // 50000
    int E = in_sizes[1] / 2;      // 800000
    const int* e_src = ei;
    const int* e_dst = ei + E;

    char* ws = (char*)d_ws;
    size_t off = 0;
    auto carve = [&](size_t bytes) -> void* {
        void* p = ws + off;
        off += (bytes + 255) & ~(size_t)255;
        return p;
    };
    int*   counts   = (int*)  carve((size_t)N * 4);        // becomes row_end
    int*   row_ptr  = (int*)  carve((size_t)N * 4);
    int*   blockSums= (int*)  carve(64 * 4);
    float* dis      = (float*)carve((size_t)N * 4);
    int*   csr_src  = (int*)  carve((size_t)E * 4);
    short* bufA     = (short*)carve((size_t)N * 128 * 2);  // bf16 Z1'/Z2'; aliased by `bucketed` pre-GEMM
    short* bufB     = (short*)carve((size_t)N * 128 * 2);  // bf16 h; aliased by `hist` pre-GEMM
    short* w1t      = (short*)carve(128 * 256 * 2);        // bf16 W1^T [n][k]
    short* wcatt    = (short*)carve(128 * 128 * 2);        // bf16 [Wmu|Wlv]^T [n][k]

    // CSR-build scratch aliases the feature buffers (build fully precedes GEMMs)
    int2* bucketed = (int2*)bufA;          // E * 8B <= N*256B
    int*  hist     = (int*)bufB;           // K*B * 4B (~154 KB)

    int nb = (N + 1023) / 1024;
    int B = (E + EPB - 1) / EPB;           // edge blocks
    int K = (N + 255) >> NB_SHIFT;         // dst buckets (<=1024 for N<=262144)

    hipLaunchKernelGGL(init_counts, dim3((N + 255) / 256), dim3(256), 0, stream, counts, N);
    hipLaunchKernelGGL(count_edges, dim3((E + 255) / 256), dim3(256), 0, stream, e_dst, counts, E);
    hipLaunchKernelGGL(scan_blocks, dim3(nb), dim3(1024), 0, stream, counts, row_ptr, blockSums, N);
    hipLaunchKernelGGL(scan_sums, dim3(1), dim3(64), 0, stream, blockSums, nb);
    hipLaunchKernelGGL(finalize_scan, dim3(nb), dim3(1024), 0, stream, row_ptr, blockSums, counts, dis, N);
    // bucketed CSR build
    hipLaunchKernelGGL(bucket_hist, dim3(B), dim3(256), 0, stream, e_dst, E, B, K, hist);
    hipLaunchKernelGGL(scan_hist, dim3(1), dim3(1024), 0, stream, hist, K * B);
    hipLaunchKernelGGL(bucket_scatter, dim3(B), dim3(256), 0, stream, e_src, e_dst, E, B, K, hist, bucketed);
    hipLaunchKernelGGL(fill_csr_bucketed, dim3(K), dim3(256), 0, stream,
                       bucketed, hist, B, K, E, row_ptr, csr_src, N);
    // weight packs
    hipLaunchKernelGGL(pack_w1t, dim3(128), dim3(256), 0, stream, W1, w1t);
    hipLaunchKernelGGL(pack_wcat_t, dim3(64), dim3(256), 0, stream, Wmu, Wlv, wcatt);
    // layer 1: Z1' = dis .* (x @ W1) ; h = leaky(dis .* Agg(Z1') + b1)
    hipLaunchKernelGGL((gemm_mfma<false>), dim3((N + 63) / 64), dim3(256), 0, stream,
                       (const void*)x, w1t, bufA, N, 256, dis);
    hipLaunchKernelGGL(agg_layer1, dim3((N + 3) / 4), dim3(256), 0, stream,
                       bufA, row_ptr, counts, csr_src, dis, b1, bufB, N);
    // layer 2 (mu & logvar share the aggregation): Z2' = dis .* (h @ [Wmu|Wlv])
    hipLaunchKernelGGL((gemm_mfma<true>), dim3((N + 63) / 64), dim3(256), 0, stream,
                       (const void*)bufB, wcatt, bufA, N, 128, dis);
    hipLaunchKernelGGL(agg_layer2, dim3((N + 3) / 4), dim3(256), 0, stream,
                       bufA, row_ptr, counts, csr_src, dis, bmu, blv, out, N);
}

// Round 6
// 305.603 us; speedup vs baseline: 1.1664x; 1.1664x over previous
//
#include <hip/hip_runtime.h>

#define NEG_SLOPE 0.01f
#define EPB 4096          // edges per block in bucket build
#define NB_SHIFT 8        // 256 dst-nodes per bucket

typedef __attribute__((ext_vector_type(8))) short bf16x8;
typedef __attribute__((ext_vector_type(4))) float floatx4;

__device__ __forceinline__ short f2bf(float f) {
    union { float f; unsigned u; } v; v.f = f;
    unsigned u = v.u;
    u += 0x7FFF + ((u >> 16) & 1);          // round-to-nearest-even
    return (short)(u >> 16);
}
__device__ __forceinline__ float bf2f(short s) {
    union { unsigned u; float f; } v;
    v.u = ((unsigned)(unsigned short)s) << 16;
    return v.f;
}

// ---------------- degree / row_ptr ----------------

__global__ void init_counts(int* counts, int n) {
    int i = blockIdx.x * blockDim.x + threadIdx.x;
    if (i < n) counts[i] = 0;
}

__global__ void count_edges(const int* __restrict__ dst, int* counts, int E) {
    int e = blockIdx.x * blockDim.x + threadIdx.x;
    if (e < E) atomicAdd(&counts[dst[e]], 1);
}

// per-1024-block exclusive scan; blockSums[b] = block total
__global__ void scan_blocks(const int* __restrict__ counts, int* row_ptr,
                            int* blockSums, int n) {
    int tid = threadIdx.x;
    int gid = blockIdx.x * 1024 + tid;
    int v = (gid < n) ? counts[gid] : 0;
    int lane = tid & 63, wave = tid >> 6;
    __shared__ int waveSums[16];
    __shared__ int waveOff[16];
    int s = v;
    #pragma unroll
    for (int off = 1; off < 64; off <<= 1) {
        int t = __shfl_up(s, off);
        if (lane >= off) s += t;
    }
    if (lane == 63) waveSums[wave] = s;
    __syncthreads();
    if (tid == 0) {
        int acc = 0;
        for (int w = 0; w < 16; w++) { waveOff[w] = acc; acc += waveSums[w]; }
        blockSums[blockIdx.x] = acc;
    }
    __syncthreads();
    if (gid < n) row_ptr[gid] = s - v + waveOff[wave];
}

__global__ void scan_sums(int* blockSums, int nb) {
    if (threadIdx.x == 0 && blockIdx.x == 0) {
        int acc = 0;
        for (int b = 0; b < nb; b++) { int t = blockSums[b]; blockSums[b] = acc; acc += t; }
    }
}

// row_ptr += blockSums[bid]; dis = rsqrt(1+count); row_end = row_ptr + count
__global__ void finalize_scan(int* row_ptr, const int* __restrict__ blockSums,
                              int* counts_to_rowend, float* dis, int n) {
    int gid = blockIdx.x * 1024 + threadIdx.x;
    if (gid < n) {
        int c = counts_to_rowend[gid];                 // original count
        dis[gid] = rsqrtf(1.0f + (float)c);            // self-loop folded into degree
        int rp = row_ptr[gid] + blockSums[blockIdx.x];
        row_ptr[gid] = rp;
        counts_to_rowend[gid] = rp + c;                // becomes row_end
    }
}

// ---------------- bucketed CSR build (XCD-local, coalesced writes) ----------------
// Bucket k holds dst in [k*256, (k+1)*256). hist layout bucket-major: hist[k*B + b].

__global__ void bucket_hist(const int* __restrict__ dst, int E, int B, int K,
                            int* __restrict__ hist) {
    __shared__ int lh[1024];
    int b = blockIdx.x;
    for (int i = threadIdx.x; i < K; i += 256) lh[i] = 0;
    __syncthreads();
    int lo = b * EPB, hi = min(lo + EPB, E);
    for (int e = lo + threadIdx.x; e < hi; e += 256)
        atomicAdd(&lh[dst[e] >> NB_SHIFT], 1);
    __syncthreads();
    for (int i = threadIdx.x; i < K; i += 256)
        hist[i * B + b] = lh[i];
}

// per-bucket exclusive scan of hist[k*B .. k*B+B), seeded with the bucket's CSR
// start row_ptr[k*256]. One 256-thread block per bucket; fully parallel.
__global__ void scan_hist_buckets(int* __restrict__ hist, const int* __restrict__ row_ptr,
                                  int B, int K) {
    __shared__ int waveTot[4];
    __shared__ int waveOff[5];
    int k = blockIdx.x;
    int tid = threadIdx.x;
    int lane = tid & 63, wave = tid >> 6;
    int* hp = hist + (size_t)k * B;
    int run = row_ptr[k << NB_SHIFT];      // bucket's global CSR start
    for (int lo = 0; lo < B; lo += 256) {
        int i = lo + tid;
        int v = (i < B) ? hp[i] : 0;
        int s = v;
        #pragma unroll
        for (int o = 1; o < 64; o <<= 1) {
            int t = __shfl_up(s, o);
            if (lane >= o) s += t;
        }
        if (lane == 63) waveTot[wave] = s;
        __syncthreads();
        if (tid == 0) {
            int acc = 0;
            #pragma unroll
            for (int w = 0; w < 4; w++) { waveOff[w] = acc; acc += waveTot[w]; }
            waveOff[4] = acc;              // chunk total
        }
        __syncthreads();
        if (i < B) hp[i] = run + s - v + waveOff[wave];
        run += waveOff[4];
        __syncthreads();                   // protect waveTot reuse
    }
}

__global__ void bucket_scatter(const int* __restrict__ src, const int* __restrict__ dst,
                               int E, int B, int K, const int* __restrict__ scanned,
                               int2* __restrict__ bucketed) {
    __shared__ int lcur[1024];
    int b = blockIdx.x;
    for (int i = threadIdx.x; i < K; i += 256) lcur[i] = scanned[i * B + b];
    __syncthreads();
    int lo = b * EPB, hi = min(lo + EPB, E);
    for (int e = lo + threadIdx.x; e < hi; e += 256) {
        int d = dst[e], sv = src[e];
        int pos = atomicAdd(&lcur[d >> NB_SHIFT], 1);
        bucketed[pos] = make_int2(sv, d);
    }
}

// one block per bucket: all CSR writes for this dst-range come from one block
__global__ void fill_csr_bucketed(const int2* __restrict__ bucketed, int K, int E,
                                  const int* __restrict__ row_ptr,
                                  int* __restrict__ csr_src, int N) {
    __shared__ int lcur[256];
    int k = blockIdx.x;
    int base = k << NB_SHIFT;
    {
        int node = base + threadIdx.x;
        lcur[threadIdx.x] = (node < N) ? row_ptr[node] : 0;
    }
    __syncthreads();
    int lo = row_ptr[base];
    int hi = (k + 1 < K) ? row_ptr[(k + 1) << NB_SHIFT] : E;
    for (int e = lo + threadIdx.x; e < hi; e += 256) {
        int2 sd = bucketed[e];
        int pos = atomicAdd(&lcur[sd.y - base], 1);
        csr_src[pos] = sd.x;
    }
}

// ---------------- weight pack: fp32 [K][N] -> bf16 transposed [N][K] ----------------

__global__ void pack_w1t(const float* __restrict__ W1, short* __restrict__ W1t) {
    int i = blockIdx.x * blockDim.x + threadIdx.x;   // i = n*256 + k, n<128, k<256
    if (i < 128 * 256) {
        int n = i >> 8, k = i & 255;
        W1t[i] = f2bf(W1[k * 128 + n]);
    }
}

__global__ void pack_wcat_t(const float* __restrict__ Wmu, const float* __restrict__ Wlv,
                            short* __restrict__ Wt) {
    int i = blockIdx.x * blockDim.x + threadIdx.x;   // i = n*128 + k, n<128, k<128
    if (i < 128 * 128) {
        int n = i >> 7, k = i & 127;
        float v = (n < 64) ? Wmu[k * 64 + n] : Wlv[k * 64 + (n - 64)];
        Wt[i] = f2bf(v);
    }
}

// ---------------- MFMA GEMM: C[M,128](bf16) = A[M,K] @ W (bf16 Wt[128][K]) ----------------
// No LDS: N-tile = full 128 cols. Block 256 thr = 4 waves; wave w: rows blk*64+w*16..+15.
// A frag (16x16x32): lane holds A[m=lane&15][k0+(lane>>4)*8+j]; fp32 A converts, bf16 A loads direct.
// B frag: lane holds Wt[n=lane&15 + t*16][k0+q*8+j] -> contiguous 16B bf16 load.
// C/D: col=lane&15, row=(lane>>4)*4+reg (m89-verified). Epilogue: row scale by dis[row], cvt bf16.

template<bool ABF16>
__launch_bounds__(256)
__global__ void gemm_mfma(const void* __restrict__ Ap, const short* __restrict__ Wt,
                          short* __restrict__ C, int M, int K,
                          const float* __restrict__ dis) {
    int w = threadIdx.x >> 6;
    int lane = threadIdx.x & 63;
    int ln = lane & 15;
    int q  = lane >> 4;
    int rowTile = blockIdx.x * 64 + w * 16;

    int rowA = rowTile + ln;
    if (rowA >= M) rowA = M - 1;                 // clamp; stores are guarded
    const short* bBase = Wt + q * 8;

    floatx4 acc[8];
    #pragma unroll
    for (int t = 0; t < 8; t++) acc[t] = (floatx4){0.f, 0.f, 0.f, 0.f};

    const float* aRowF = (const float*)Ap + (size_t)rowA * K + q * 8;
    const short* aRowB = (const short*)Ap + (size_t)rowA * K + q * 8;

    for (int kt = 0; kt < K; kt += 32) {
        bf16x8 aF;
        if (ABF16) {
            aF = *(const bf16x8*)(aRowB + kt);
        } else {
            float4 af0 = *(const float4*)(aRowF + kt);
            float4 af1 = *(const float4*)(aRowF + kt + 4);
            aF[0] = f2bf(af0.x); aF[1] = f2bf(af0.y); aF[2] = f2bf(af0.z); aF[3] = f2bf(af0.w);
            aF[4] = f2bf(af1.x); aF[5] = f2bf(af1.y); aF[6] = f2bf(af1.z); aF[7] = f2bf(af1.w);
        }
        bf16x8 bF[8];
        #pragma unroll
        for (int t = 0; t < 8; t++)
            bF[t] = *(const bf16x8*)(bBase + (size_t)(t * 16 + ln) * K + kt);
        #pragma unroll
        for (int t = 0; t < 8; t++)
            acc[t] = __builtin_amdgcn_mfma_f32_16x16x32_bf16(aF, bF[t], acc[t], 0, 0, 0);
    }

    #pragma unroll
    for (int reg = 0; reg < 4; reg++) {
        int r = rowTile + q * 4 + reg;
        if (r < M) {
            float s = dis ? dis[r] : 1.f;
            #pragma unroll
            for (int t = 0; t < 8; t++)
                C[(size_t)r * 128 + t * 16 + ln] = f2bf(s * acc[t][reg]);
        }
    }
}

// ---------------- aggregation: one WAVE per node, bf16 rows, quarter-wave gathers ----------------
// zp holds pre-scaled bf16 rows z'[i] = dis[i] * (transform(x))[i]  (128 feats = 256B).
// out_node = dis[d] * ( sum_{s in N(d)} z'[s] + z'[d] ) + bias

#define AGG_BODY_BF16                                                         \
    int wave = threadIdx.x >> 6;                                              \
    int node = blockIdx.x * 4 + wave;                                         \
    if (node >= N) return;                                                    \
    int lane = threadIdx.x & 63;                                              \
    int qi = lane >> 4;                                                       \
    int fl = lane & 15;                                                       \
    int fo = fl * 8;                                                          \
    const short* zb = zp + fo;                                                \
    int start = row_ptr[node], end = row_end[node];                           \
    float acc[8];                                                             \
    _Pragma("unroll")                                                         \
    for (int j = 0; j < 8; j++) acc[j] = 0.f;                                 \
    int e = start + qi;                                                       \
    for (; e + 4 < end; e += 8) {                                             \
        int s0 = csr_src[e], s1 = csr_src[e + 4];                             \
        bf16x8 z0 = *(const bf16x8*)(zb + (size_t)s0 * 128);                  \
        bf16x8 z1 = *(const bf16x8*)(zb + (size_t)s1 * 128);                  \
        _Pragma("unroll")                                                     \
        for (int j = 0; j < 8; j++) acc[j] += bf2f(z0[j]) + bf2f(z1[j]);      \
    }                                                                         \
    for (; e < end; e += 4) {                                                 \
        int s0 = csr_src[e];                                                  \
        bf16x8 z0 = *(const bf16x8*)(zb + (size_t)s0 * 128);                  \
        _Pragma("unroll")                                                     \
        for (int j = 0; j < 8; j++) acc[j] += bf2f(z0[j]);                    \
    }                                                                         \
    if (qi == 0) {  /* self loop, added exactly once */                       \
        bf16x8 zs = *(const bf16x8*)(zb + (size_t)node * 128);                \
        _Pragma("unroll")                                                     \
        for (int j = 0; j < 8; j++) acc[j] += bf2f(zs[j]);                    \
    }                                                                         \
    _Pragma("unroll")                                                         \
    for (int j = 0; j < 8; j++) {                                             \
        acc[j] += __shfl_xor(acc[j], 16);                                     \
        acc[j] += __shfl_xor(acc[j], 32);                                     \
    }

__launch_bounds__(256)
__global__ void agg_layer1(const short* __restrict__ zp, const int* __restrict__ row_ptr,
                           const int* __restrict__ row_end, const int* __restrict__ csr_src,
                           const float* __restrict__ dis, const float* __restrict__ b1,
                           short* __restrict__ h, int N) {
    AGG_BODY_BF16
    if (qi == 0) {
        float d = dis[node];
        bf16x8 ov;
        #pragma unroll
        for (int j = 0; j < 8; j++) {
            float v = fmaf(d, acc[j], b1[fo + j]);
            v = (v > 0.f) ? v : NEG_SLOPE * v;
            ov[j] = f2bf(v);
        }
        *(bf16x8*)(h + (size_t)node * 128 + fo) = ov;
    }
}

__launch_bounds__(256)
__global__ void agg_layer2(const short* __restrict__ zp, const int* __restrict__ row_ptr,
                           const int* __restrict__ row_end, const int* __restrict__ csr_src,
                           const float* __restrict__ dis, const float* __restrict__ b_mu,
                           const float* __restrict__ b_lv, float* __restrict__ out, int N) {
    AGG_BODY_BF16
    if (qi == 0) {
        float d = dis[node];
        float r[8];
        if (fl < 8) {                        // mu: features fo..fo+7
            #pragma unroll
            for (int j = 0; j < 8; j++) r[j] = fmaf(d, acc[j], b_mu[fo + j]);
            float* p = out + (size_t)node * 64 + fo;
            *(float4*)p       = make_float4(r[0], r[1], r[2], r[3]);
            *(float4*)(p + 4) = make_float4(r[4], r[5], r[6], r[7]);
        } else {                             // logvar: features fo-64..fo-57
            #pragma unroll
            for (int j = 0; j < 8; j++) r[j] = fmaf(d, acc[j], b_lv[fo - 64 + j]);
            float* p = out + (size_t)N * 64 + (size_t)node * 64 + (fo - 64);
            *(float4*)p       = make_float4(r[0], r[1], r[2], r[3]);
            *(float4*)(p + 4) = make_float4(r[4], r[5], r[6], r[7]);
        }
    }
}

// ---------------- launcher ----------------

extern "C" void kernel_launch(void* const* d_in, const int* in_sizes, int n_in,
                              void* d_out, int out_size, void* d_ws, size_t ws_size,
                              hipStream_t stream) {
    const float* x   = (const float*)d_in[0];
    const int*   ei  = (const int*)d_in[1];    // [2,E] int32: src then dst
    const float* W1  = (const float*)d_in[2];
    const float* b1  = (const float*)d_in[3];
    const float* Wmu = (const float*)d_in[4];
    const float* bmu = (const float*)d_in[5];
    const float* Wlv = (const float*)d_in[6];
    const float* blv = (const float*)d_in[7];
    float* out = (float*)d_out;

    const int F_IN = 256;
    int N = in_sizes[0] / F_IN;   // 50000
    int E = in_sizes[1] / 2;      // 800000
    const int* e_src = ei;
    const int* e_dst = ei + E;

    char* ws = (char*)d_ws;
    size_t off = 0;
    auto carve = [&](size_t bytes) -> void* {
        void* p = ws + off;
        off += (bytes + 255) & ~(size_t)255;
        return p;
    };
    int*   counts   = (int*)  carve((size_t)N * 4);        // becomes row_end
    int*   row_ptr  = (int*)  carve((size_t)N * 4);
    int*   blockSums= (int*)  carve(64 * 4);
    float* dis      = (float*)carve((size_t)N * 4);
    int*   csr_src  = (int*)  carve((size_t)E * 4);
    short* bufA     = (short*)carve((size_t)N * 128 * 2);  // bf16 Z1'/Z2'; aliased by `bucketed` pre-GEMM
    short* bufB     = (short*)carve((size_t)N * 128 * 2);  // bf16 h; aliased by `hist` pre-GEMM
    short* w1t      = (short*)carve(128 * 256 * 2);        // bf16 W1^T [n][k]
    short* wcatt    = (short*)carve(128 * 128 * 2);        // bf16 [Wmu|Wlv]^T [n][k]

    // CSR-build scratch aliases the feature buffers (build fully precedes GEMMs)
    int2* bucketed = (int2*)bufA;          // E * 8B <= N*256B
    int*  hist     = (int*)bufB;           // K*B * 4B (~154 KB)

    int nb = (N + 1023) / 1024;
    int B = (E + EPB - 1) / EPB;           // edge blocks
    int K = (N + 255) >> NB_SHIFT;         // dst buckets

    hipLaunchKernelGGL(init_counts, dim3((N + 255) / 256), dim3(256), 0, stream, counts, N);
    hipLaunchKernelGGL(count_edges, dim3((E + 255) / 256), dim3(256), 0, stream, e_dst, counts, E);
    hipLaunchKernelGGL(scan_blocks, dim3(nb), dim3(1024), 0, stream, counts, row_ptr, blockSums, N);
    hipLaunchKernelGGL(scan_sums, dim3(1), dim3(64), 0, stream, blockSums, nb);
    hipLaunchKernelGGL(finalize_scan, dim3(nb), dim3(1024), 0, stream, row_ptr, blockSums, counts, dis, N);
    // bucketed CSR build (per-bucket scans only; no global serial scan)
    hipLaunchKernelGGL(bucket_hist, dim3(B), dim3(256), 0, stream, e_dst, E, B, K, hist);
    hipLaunchKernelGGL(scan_hist_buckets, dim3(K), dim3(256), 0, stream, hist, row_ptr, B, K);
    hipLaunchKernelGGL(bucket_scatter, dim3(B), dim3(256), 0, stream, e_src, e_dst, E, B, K, hist, bucketed);
    hipLaunchKernelGGL(fill_csr_bucketed, dim3(K), dim3(256), 0, stream,
                       bucketed, K, E, row_ptr, csr_src, N);
    // weight packs
    hipLaunchKernelGGL(pack_w1t, dim3(128), dim3(256), 0, stream, W1, w1t);
    hipLaunchKernelGGL(pack_wcat_t, dim3(64), dim3(256), 0, stream, Wmu, Wlv, wcatt);
    // layer 1: Z1' = dis .* (x @ W1) ; h = leaky(dis .* Agg(Z1') + b1)
    hipLaunchKernelGGL((gemm_mfma<false>), dim3((N + 63) / 64), dim3(256), 0, stream,
                       (const void*)x, w1t, bufA, N, 256, dis);
    hipLaunchKernelGGL(agg_layer1, dim3((N + 3) / 4), dim3(256), 0, stream,
                       bufA, row_ptr, counts, csr_src, dis, b1, bufB, N);
    // layer 2 (mu & logvar share the aggregation): Z2' = dis .* (h @ [Wmu|Wlv])
    hipLaunchKernelGGL((gemm_mfma<true>), dim3((N + 63) / 64), dim3(256), 0, stream,
                       (const void*)bufB, wcatt, bufA, N, 128, dis);
    hipLaunchKernelGGL(agg_layer2, dim3((N + 3) / 4), dim3(256), 0, stream,
                       bufA, row_ptr, counts, csr_src, dis, bmu, blv, out, N);
}

// Round 7
// 280.422 us; speedup vs baseline: 1.2711x; 1.0898x over previous
//
#include <hip/hip_runtime.h>

#define NEG_SLOPE 0.01f
#define EPB 4096          // edges per block in bucket build
#define NB_SHIFT 8        // 256 dst-nodes per bucket

typedef __attribute__((ext_vector_type(8))) short bf16x8;
typedef __attribute__((ext_vector_type(4))) float floatx4;

__device__ __forceinline__ short f2bf(float f) {
    union { float f; unsigned u; } v; v.f = f;
    unsigned u = v.u;
    u += 0x7FFF + ((u >> 16) & 1);          // round-to-nearest-even
    return (short)(u >> 16);
}
__device__ __forceinline__ float bf2f(short s) {
    union { unsigned u; float f; } v;
    v.u = ((unsigned)(unsigned short)s) << 16;
    return v.f;
}

// ---------------- degree / row_ptr ----------------

__global__ void init_counts(int* counts, int n) {
    int i = blockIdx.x * blockDim.x + threadIdx.x;
    if (i < n) counts[i] = 0;
}

__global__ void count_edges(const int* __restrict__ dst, int* counts, int E) {
    int e = blockIdx.x * blockDim.x + threadIdx.x;
    if (e < E) atomicAdd(&counts[dst[e]], 1);
}

// per-1024-block exclusive scan; blockSums[b] = block total
__global__ void scan_blocks(const int* __restrict__ counts, int* row_ptr,
                            int* blockSums, int n) {
    int tid = threadIdx.x;
    int gid = blockIdx.x * 1024 + tid;
    int v = (gid < n) ? counts[gid] : 0;
    int lane = tid & 63, wave = tid >> 6;
    __shared__ int waveSums[16];
    __shared__ int waveOff[16];
    int s = v;
    #pragma unroll
    for (int off = 1; off < 64; off <<= 1) {
        int t = __shfl_up(s, off);
        if (lane >= off) s += t;
    }
    if (lane == 63) waveSums[wave] = s;
    __syncthreads();
    if (tid == 0) {
        int acc = 0;
        for (int w = 0; w < 16; w++) { waveOff[w] = acc; acc += waveSums[w]; }
        blockSums[blockIdx.x] = acc;
    }
    __syncthreads();
    if (gid < n) row_ptr[gid] = s - v + waveOff[wave];
}

__global__ void scan_sums(int* blockSums, int nb) {
    if (threadIdx.x == 0 && blockIdx.x == 0) {
        int acc = 0;
        for (int b = 0; b < nb; b++) { int t = blockSums[b]; blockSums[b] = acc; acc += t; }
    }
}

// row_ptr += blockSums[bid]; dis = rsqrt(1+count); row_end = row_ptr + count
__global__ void finalize_scan(int* row_ptr, const int* __restrict__ blockSums,
                              int* counts_to_rowend, float* dis, int n) {
    int gid = blockIdx.x * 1024 + threadIdx.x;
    if (gid < n) {
        int c = counts_to_rowend[gid];                 // original count
        dis[gid] = rsqrtf(1.0f + (float)c);            // self-loop folded into degree
        int rp = row_ptr[gid] + blockSums[blockIdx.x];
        row_ptr[gid] = rp;
        counts_to_rowend[gid] = rp + c;                // becomes row_end
    }
}

// ---------------- bucketed CSR build (XCD-local, coalesced writes) ----------------
// Bucket k holds dst in [k*256, (k+1)*256). hist layout bucket-major: hist[k*B + b].

__global__ void bucket_hist(const int* __restrict__ dst, int E, int B, int K,
                            int* __restrict__ hist) {
    __shared__ int lh[1024];
    int b = blockIdx.x;
    for (int i = threadIdx.x; i < K; i += 256) lh[i] = 0;
    __syncthreads();
    int lo = b * EPB, hi = min(lo + EPB, E);
    for (int e = lo + threadIdx.x; e < hi; e += 256)
        atomicAdd(&lh[dst[e] >> NB_SHIFT], 1);
    __syncthreads();
    for (int i = threadIdx.x; i < K; i += 256)
        hist[i * B + b] = lh[i];
}

// per-bucket exclusive scan of hist[k*B .. k*B+B), seeded with the bucket's CSR
// start row_ptr[k*256]. One 256-thread block per bucket; fully parallel.
__global__ void scan_hist_buckets(int* __restrict__ hist, const int* __restrict__ row_ptr,
                                  int B, int K) {
    __shared__ int waveTot[4];
    __shared__ int waveOff[5];
    int k = blockIdx.x;
    int tid = threadIdx.x;
    int lane = tid & 63, wave = tid >> 6;
    int* hp = hist + (size_t)k * B;
    int run = row_ptr[k << NB_SHIFT];      // bucket's global CSR start
    for (int lo = 0; lo < B; lo += 256) {
        int i = lo + tid;
        int v = (i < B) ? hp[i] : 0;
        int s = v;
        #pragma unroll
        for (int o = 1; o < 64; o <<= 1) {
            int t = __shfl_up(s, o);
            if (lane >= o) s += t;
        }
        if (lane == 63) waveTot[wave] = s;
        __syncthreads();
        if (tid == 0) {
            int acc = 0;
            #pragma unroll
            for (int w = 0; w < 4; w++) { waveOff[w] = acc; acc += waveTot[w]; }
            waveOff[4] = acc;              // chunk total
        }
        __syncthreads();
        if (i < B) hp[i] = run + s - v + waveOff[wave];
        run += waveOff[4];
        __syncthreads();                   // protect waveTot reuse
    }
}

__global__ void bucket_scatter(const int* __restrict__ src, const int* __restrict__ dst,
                               int E, int B, int K, const int* __restrict__ scanned,
                               int2* __restrict__ bucketed) {
    __shared__ int lcur[1024];
    int b = blockIdx.x;
    for (int i = threadIdx.x; i < K; i += 256) lcur[i] = scanned[i * B + b];
    __syncthreads();
    int lo = b * EPB, hi = min(lo + EPB, E);
    for (int e = lo + threadIdx.x; e < hi; e += 256) {
        int d = dst[e], sv = src[e];
        int pos = atomicAdd(&lcur[d >> NB_SHIFT], 1);
        bucketed[pos] = make_int2(sv, d);
    }
}

// one block per bucket: all CSR writes for this dst-range come from one block
__global__ void fill_csr_bucketed(const int2* __restrict__ bucketed, int K, int E,
                                  const int* __restrict__ row_ptr,
                                  int* __restrict__ csr_src, int N) {
    __shared__ int lcur[256];
    int k = blockIdx.x;
    int base = k << NB_SHIFT;
    {
        int node = base + threadIdx.x;
        lcur[threadIdx.x] = (node < N) ? row_ptr[node] : 0;
    }
    __syncthreads();
    int lo = row_ptr[base];
    int hi = (k + 1 < K) ? row_ptr[(k + 1) << NB_SHIFT] : E;
    for (int e = lo + threadIdx.x; e < hi; e += 256) {
        int2 sd = bucketed[e];
        int pos = atomicAdd(&lcur[sd.y - base], 1);
        csr_src[pos] = sd.x;
    }
}

// ---------------- weight pack: fp32 [K][Nout] -> bf16 in MFMA FRAGMENT ORDER ----------------
// Frag order: flat = (kb*8 + t)*512 + lane*8 + j, lane = q*16 + ln,
// holding W[k = kb*32 + q*8 + j][n = t*16 + ln]. A wave's B-frag load for
// (kb, t) is then one contiguous 1KB burst at offset (kb*8+t)*1024 bytes.

template<int K>
__global__ void pack_w_frag(const float* __restrict__ W, short* __restrict__ out) {
    int i = blockIdx.x * blockDim.x + threadIdx.x;   // < 128*K
    if (i < 128 * K) {
        int j  = i & 7;
        int ln = (i >> 3) & 15;
        int q  = (i >> 7) & 3;
        int t  = (i >> 9) & 7;
        int kb = i >> 12;
        int n = t * 16 + ln;
        int k = kb * 32 + q * 8 + j;
        out[i] = f2bf(W[k * 128 + n]);
    }
}

template<int K>
__global__ void pack_wcat_frag(const float* __restrict__ Wmu, const float* __restrict__ Wlv,
                               short* __restrict__ out) {
    int i = blockIdx.x * blockDim.x + threadIdx.x;   // < 128*K
    if (i < 128 * K) {
        int j  = i & 7;
        int ln = (i >> 3) & 15;
        int q  = (i >> 7) & 3;
        int t  = (i >> 9) & 7;
        int kb = i >> 12;
        int n = t * 16 + ln;
        int k = kb * 32 + q * 8 + j;
        out[i] = f2bf((n < 64) ? Wmu[k * 64 + n] : Wlv[k * 64 + (n - 64)]);
    }
}

// ---------------- MFMA GEMM: C[M,128](bf16) = A[M,K] @ W (bf16 frag-order) ----------------
// Block 256 thr = 4 waves; wave w: rows blk*128 + w*32 .. +31 (two 16-row A frags).
// B frag (kb,t): contiguous 1KB burst from Bfrag. A frag: lane (ln,q) holds
// A[rowTile + f*16 + ln][kb*32 + q*8 + j]. C/D: col=lane&15, row=q*4+reg (m89).
// Epilogue: scale row by dis[row], convert bf16.

template<int K, bool ABF16>
__launch_bounds__(256)
__global__ void gemm_mfma(const void* __restrict__ Ap, const short* __restrict__ Bfrag,
                          short* __restrict__ C, int M, const float* __restrict__ dis) {
    int w = threadIdx.x >> 6;
    int lane = threadIdx.x & 63;
    int ln = lane & 15;
    int q  = lane >> 4;
    int rowTile = blockIdx.x * 128 + w * 32;

    int r0 = rowTile + ln;
    int r1 = rowTile + 16 + ln;
    int r0c = (r0 < M) ? r0 : (M - 1);
    int r1c = (r1 < M) ? r1 : (M - 1);

    const float* a0F = (const float*)Ap + (size_t)r0c * K + q * 8;
    const float* a1F = (const float*)Ap + (size_t)r1c * K + q * 8;
    const short* a0B = (const short*)Ap + (size_t)r0c * K + q * 8;
    const short* a1B = (const short*)Ap + (size_t)r1c * K + q * 8;
    const short* bLane = Bfrag + lane * 8;

    floatx4 acc[2][8];
    #pragma unroll
    for (int f = 0; f < 2; f++)
        #pragma unroll
        for (int t = 0; t < 8; t++) acc[f][t] = (floatx4){0.f, 0.f, 0.f, 0.f};

    constexpr int NIT = K / 32;
    #pragma unroll
    for (int kb = 0; kb < NIT; kb++) {
        int kt = kb * 32;
        bf16x8 aF0, aF1;
        if (ABF16) {
            aF0 = *(const bf16x8*)(a0B + kt);
            aF1 = *(const bf16x8*)(a1B + kt);
        } else {
            float4 x0 = *(const float4*)(a0F + kt);
            float4 x1 = *(const float4*)(a0F + kt + 4);
            float4 y0 = *(const float4*)(a1F + kt);
            float4 y1 = *(const float4*)(a1F + kt + 4);
            aF0[0] = f2bf(x0.x); aF0[1] = f2bf(x0.y); aF0[2] = f2bf(x0.z); aF0[3] = f2bf(x0.w);
            aF0[4] = f2bf(x1.x); aF0[5] = f2bf(x1.y); aF0[6] = f2bf(x1.z); aF0[7] = f2bf(x1.w);
            aF1[0] = f2bf(y0.x); aF1[1] = f2bf(y0.y); aF1[2] = f2bf(y0.z); aF1[3] = f2bf(y0.w);
            aF1[4] = f2bf(y1.x); aF1[5] = f2bf(y1.y); aF1[6] = f2bf(y1.z); aF1[7] = f2bf(y1.w);
        }
        bf16x8 bF[8];
        #pragma unroll
        for (int t = 0; t < 8; t++)
            bF[t] = *(const bf16x8*)(bLane + (size_t)(kb * 8 + t) * 512);
        #pragma unroll
        for (int t = 0; t < 8; t++) {
            acc[0][t] = __builtin_amdgcn_mfma_f32_16x16x32_bf16(aF0, bF[t], acc[0][t], 0, 0, 0);
            acc[1][t] = __builtin_amdgcn_mfma_f32_16x16x32_bf16(aF1, bF[t], acc[1][t], 0, 0, 0);
        }
    }

    #pragma unroll
    for (int f = 0; f < 2; f++) {
        #pragma unroll
        for (int reg = 0; reg < 4; reg++) {
            int r = rowTile + f * 16 + q * 4 + reg;
            if (r < M) {
                float s = dis ? dis[r] : 1.f;
                #pragma unroll
                for (int t = 0; t < 8; t++)
                    C[(size_t)r * 128 + t * 16 + ln] = f2bf(s * acc[f][t][reg]);
            }
        }
    }
}

// ---------------- aggregation: one WAVE per node, bf16 rows, quarter-wave gathers ----------------
// zp holds pre-scaled bf16 rows z'[i] = dis[i] * (transform(x))[i]  (128 feats = 256B).
// out_node = dis[d] * ( sum_{s in N(d)} z'[s] + z'[d] ) + bias

#define AGG_BODY_BF16                                                         \
    int wave = threadIdx.x >> 6;                                              \
    int node = blockIdx.x * 4 + wave;                                         \
    if (node >= N) return;                                                    \
    int lane = threadIdx.x & 63;                                              \
    int qi = lane >> 4;                                                       \
    int fl = lane & 15;                                                       \
    int fo = fl * 8;                                                          \
    const short* zb = zp + fo;                                                \
    int start = row_ptr[node], end = row_end[node];                           \
    float acc[8];                                                             \
    _Pragma("unroll")                                                         \
    for (int j = 0; j < 8; j++) acc[j] = 0.f;                                 \
    int e = start + qi;                                                       \
    for (; e + 4 < end; e += 8) {                                             \
        int s0 = csr_src[e], s1 = csr_src[e + 4];                             \
        bf16x8 z0 = *(const bf16x8*)(zb + (size_t)s0 * 128);                  \
        bf16x8 z1 = *(const bf16x8*)(zb + (size_t)s1 * 128);                  \
        _Pragma("unroll")                                                     \
        for (int j = 0; j < 8; j++) acc[j] += bf2f(z0[j]) + bf2f(z1[j]);      \
    }                                                                         \
    for (; e < end; e += 4) {                                                 \
        int s0 = csr_src[e];                                                  \
        bf16x8 z0 = *(const bf16x8*)(zb + (size_t)s0 * 128);                  \
        _Pragma("unroll")                                                     \
        for (int j = 0; j < 8; j++) acc[j] += bf2f(z0[j]);                    \
    }                                                                         \
    if (qi == 0) {  /* self loop, added exactly once */                       \
        bf16x8 zs = *(const bf16x8*)(zb + (size_t)node * 128);                \
        _Pragma("unroll")                                                     \
        for (int j = 0; j < 8; j++) acc[j] += bf2f(zs[j]);                    \
    }                                                                         \
    _Pragma("unroll")                                                         \
    for (int j = 0; j < 8; j++) {                                             \
        acc[j] += __shfl_xor(acc[j], 16);                                     \
        acc[j] += __shfl_xor(acc[j], 32);                                     \
    }

__launch_bounds__(256)
__global__ void agg_layer1(const short* __restrict__ zp, const int* __restrict__ row_ptr,
                           const int* __restrict__ row_end, const int* __restrict__ csr_src,
                           const float* __restrict__ dis, const float* __restrict__ b1,
                           short* __restrict__ h, int N) {
    AGG_BODY_BF16
    if (qi == 0) {
        float d = dis[node];
        bf16x8 ov;
        #pragma unroll
        for (int j = 0; j < 8; j++) {
            float v = fmaf(d, acc[j], b1[fo + j]);
            v = (v > 0.f) ? v : NEG_SLOPE * v;
            ov[j] = f2bf(v);
        }
        *(bf16x8*)(h + (size_t)node * 128 + fo) = ov;
    }
}

__launch_bounds__(256)
__global__ void agg_layer2(const short* __restrict__ zp, const int* __restrict__ row_ptr,
                           const int* __restrict__ row_end, const int* __restrict__ csr_src,
                           const float* __restrict__ dis, const float* __restrict__ b_mu,
                           const float* __restrict__ b_lv, float* __restrict__ out, int N) {
    AGG_BODY_BF16
    if (qi == 0) {
        float d = dis[node];
        float r[8];
        if (fl < 8) {                        // mu: features fo..fo+7
            #pragma unroll
            for (int j = 0; j < 8; j++) r[j] = fmaf(d, acc[j], b_mu[fo + j]);
            float* p = out + (size_t)node * 64 + fo;
            *(float4*)p       = make_float4(r[0], r[1], r[2], r[3]);
            *(float4*)(p + 4) = make_float4(r[4], r[5], r[6], r[7]);
        } else {                             // logvar: features fo-64..fo-57
            #pragma unroll
            for (int j = 0; j < 8; j++) r[j] = fmaf(d, acc[j], b_lv[fo - 64 + j]);
            float* p = out + (size_t)N * 64 + (size_t)node * 64 + (fo - 64);
            *(float4*)p       = make_float4(r[0], r[1], r[2], r[3]);
            *(float4*)(p + 4) = make_float4(r[4], r[5], r[6], r[7]);
        }
    }
}

// ---------------- launcher ----------------

extern "C" void kernel_launch(void* const* d_in, const int* in_sizes, int n_in,
                              void* d_out, int out_size, void* d_ws, size_t ws_size,
                              hipStream_t stream) {
    const float* x   = (const float*)d_in[0];
    const int*   ei  = (const int*)d_in[1];    // [2,E] int32: src then dst
    const float* W1  = (const float*)d_in[2];
    const float* b1  = (const float*)d_in[3];
    const float* Wmu = (const float*)d_in[4];
    const float* bmu = (const float*)d_in[5];
    const float* Wlv = (const float*)d_in[6];
    const float* blv = (const float*)d_in[7];
    float* out = (float*)d_out;

    const int F_IN = 256;
    int N = in_sizes[0] / F_IN;   // 50000
    int E = in_sizes[1] / 2;      // 800000
    const int* e_src = ei;
    const int* e_dst = ei + E;

    char* ws = (char*)d_ws;
    size_t off = 0;
    auto carve = [&](size_t bytes) -> void* {
        void* p = ws + off;
        off += (bytes + 255) & ~(size_t)255;
        return p;
    };
    int*   counts   = (int*)  carve((size_t)N * 4);        // becomes row_end
    int*   row_ptr  = (int*)  carve((size_t)N * 4);
    int*   blockSums= (int*)  carve(64 * 4);
    float* dis      = (float*)carve((size_t)N * 4);
    int*   csr_src  = (int*)  carve((size_t)E * 4);
    short* bufA     = (short*)carve((size_t)N * 128 * 2);  // bf16 Z1'/Z2'; aliased by `bucketed` pre-GEMM
    short* bufB     = (short*)carve((size_t)N * 128 * 2);  // bf16 h; aliased by `hist` pre-GEMM
    short* w1f      = (short*)carve(128 * 256 * 2);        // bf16 W1 frag-order
    short* wcatf    = (short*)carve(128 * 128 * 2);        // bf16 [Wmu|Wlv] frag-order

    // CSR-build scratch aliases the feature buffers (build fully precedes GEMMs)
    int2* bucketed = (int2*)bufA;          // E * 8B <= N*256B
    int*  hist     = (int*)bufB;           // K*B * 4B (~154 KB)

    int nb = (N + 1023) / 1024;
    int B = (E + EPB - 1) / EPB;           // edge blocks
    int K = (N + 255) >> NB_SHIFT;         // dst buckets

    hipLaunchKernelGGL(init_counts, dim3((N + 255) / 256), dim3(256), 0, stream, counts, N);
    hipLaunchKernelGGL(count_edges, dim3((E + 255) / 256), dim3(256), 0, stream, e_dst, counts, E);
    hipLaunchKernelGGL(scan_blocks, dim3(nb), dim3(1024), 0, stream, counts, row_ptr, blockSums, N);
    hipLaunchKernelGGL(scan_sums, dim3(1), dim3(64), 0, stream, blockSums, nb);
    hipLaunchKernelGGL(finalize_scan, dim3(nb), dim3(1024), 0, stream, row_ptr, blockSums, counts, dis, N);
    // bucketed CSR build (per-bucket scans only; no global serial scan)
    hipLaunchKernelGGL(bucket_hist, dim3(B), dim3(256), 0, stream, e_dst, E, B, K, hist);
    hipLaunchKernelGGL(scan_hist_buckets, dim3(K), dim3(256), 0, stream, hist, row_ptr, B, K);
    hipLaunchKernelGGL(bucket_scatter, dim3(B), dim3(256), 0, stream, e_src, e_dst, E, B, K, hist, bucketed);
    hipLaunchKernelGGL(fill_csr_bucketed, dim3(K), dim3(256), 0, stream,
                       bucketed, K, E, row_ptr, csr_src, N);
    // weight packs (frag order)
    hipLaunchKernelGGL((pack_w_frag<256>), dim3(128), dim3(256), 0, stream, W1, w1f);
    hipLaunchKernelGGL((pack_wcat_frag<128>), dim3(64), dim3(256), 0, stream, Wmu, Wlv, wcatf);
    // layer 1: Z1' = dis .* (x @ W1) ; h = leaky(dis .* Agg(Z1') + b1)
    hipLaunchKernelGGL((gemm_mfma<256, false>), dim3((N + 127) / 128), dim3(256), 0, stream,
                       (const void*)x, w1f, bufA, N, dis);
    hipLaunchKernelGGL(agg_layer1, dim3((N + 3) / 4), dim3(256), 0, stream,
                       bufA, row_ptr, counts, csr_src, dis, b1, bufB, N);
    // layer 2 (mu & logvar share the aggregation): Z2' = dis .* (h @ [Wmu|Wlv])
    hipLaunchKernelGGL((gemm_mfma<128, true>), dim3((N + 127) / 128), dim3(256), 0, stream,
                       (const void*)bufB, wcatf, bufA, N, dis);
    hipLaunchKernelGGL(agg_layer2, dim3((N + 3) / 4), dim3(256), 0, stream,
                       bufA, row_ptr, counts, csr_src, dis, bmu, blv, out, N);
}

// Round 8
// 255.254 us; speedup vs baseline: 1.3964x; 1.0986x over previous
//
#include <hip/hip_runtime.h>

#define NEG_SLOPE 0.01f
#define EPB 4096          // edges per block in bucket build
#define NB_SHIFT 8        // 256 dst-nodes per bucket

typedef __attribute__((ext_vector_type(8))) short bf16x8;
typedef __attribute__((ext_vector_type(4))) float floatx4;

__device__ __forceinline__ short f2bf(float f) {
    union { float f; unsigned u; } v; v.f = f;
    unsigned u = v.u;
    u += 0x7FFF + ((u >> 16) & 1);          // round-to-nearest-even
    return (short)(u >> 16);
}
__device__ __forceinline__ float bf2f(short s) {
    union { unsigned u; float f; } v;
    v.u = ((unsigned)(unsigned short)s) << 16;
    return v.f;
}

// ---------------- bucketed CSR build (degrees derived in-bucket; no global scan) ----------------
// Bucket k holds dst in [k*256, (k+1)*256). hist layout bucket-major: hist[k*B + b].

__global__ void bucket_hist(const int* __restrict__ dst, int E, int B, int K,
                            int* __restrict__ hist) {
    __shared__ int lh[1024];
    int b = blockIdx.x;
    for (int i = threadIdx.x; i < K; i += 256) lh[i] = 0;
    __syncthreads();
    int lo = b * EPB, hi = min(lo + EPB, E);
    for (int e = lo + threadIdx.x; e < hi; e += 256)
        atomicAdd(&lh[dst[e] >> NB_SHIFT], 1);
    __syncthreads();
    for (int i = threadIdx.x; i < K; i += 256)
        hist[i * B + b] = lh[i];
}

// one block: bucket totals + exclusive scan -> bstart[0..K], bstart[K]=E
__global__ void bucket_starts(const int* __restrict__ hist, int B, int K, int E,
                              int* __restrict__ bstart) {
    __shared__ int tot[1024];
    __shared__ int waveTot[4];
    __shared__ int waveOff[5];
    int tid = threadIdx.x;                 // 256 threads
    for (int k = tid; k < K; k += 256) {
        const int* hp = hist + (size_t)k * B;
        int s = 0;
        for (int b = 0; b < B; b++) s += hp[b];
        tot[k] = s;
    }
    __syncthreads();
    int lane = tid & 63, wave = tid >> 6;
    int run = 0;
    for (int lo = 0; lo < K; lo += 256) {
        int i = lo + tid;
        int v = (i < K) ? tot[i] : 0;
        int s = v;
        #pragma unroll
        for (int o = 1; o < 64; o <<= 1) {
            int t = __shfl_up(s, o);
            if (lane >= o) s += t;
        }
        if (lane == 63) waveTot[wave] = s;
        __syncthreads();
        if (tid == 0) {
            int acc = 0;
            #pragma unroll
            for (int w = 0; w < 4; w++) { waveOff[w] = acc; acc += waveTot[w]; }
            waveOff[4] = acc;
        }
        __syncthreads();
        if (i < K) bstart[i] = run + s - v + waveOff[wave];
        run += waveOff[4];
        __syncthreads();
    }
    if (tid == 0) bstart[K] = E;
}

// per-bucket exclusive scan of hist[k*B .. k*B+B), seeded with bstart[k].
__global__ void scan_hist_buckets(int* __restrict__ hist, const int* __restrict__ bstart,
                                  int B, int K) {
    __shared__ int waveTot[4];
    __shared__ int waveOff[5];
    int k = blockIdx.x;
    int tid = threadIdx.x;
    int lane = tid & 63, wave = tid >> 6;
    int* hp = hist + (size_t)k * B;
    int run = bstart[k];
    for (int lo = 0; lo < B; lo += 256) {
        int i = lo + tid;
        int v = (i < B) ? hp[i] : 0;
        int s = v;
        #pragma unroll
        for (int o = 1; o < 64; o <<= 1) {
            int t = __shfl_up(s, o);
            if (lane >= o) s += t;
        }
        if (lane == 63) waveTot[wave] = s;
        __syncthreads();
        if (tid == 0) {
            int acc = 0;
            #pragma unroll
            for (int w = 0; w < 4; w++) { waveOff[w] = acc; acc += waveTot[w]; }
            waveOff[4] = acc;
        }
        __syncthreads();
        if (i < B) hp[i] = run + s - v + waveOff[wave];
        run += waveOff[4];
        __syncthreads();
    }
}

// scatter edges into bucket-contiguous order; 4B records: src | local_dst<<24 (needs N < 2^24)
__global__ void bucket_scatter(const int* __restrict__ src, const int* __restrict__ dst,
                               int E, int B, int K, const int* __restrict__ scanned,
                               unsigned* __restrict__ bucketed) {
    __shared__ int lcur[1024];
    int b = blockIdx.x;
    for (int i = threadIdx.x; i < K; i += 256) lcur[i] = scanned[i * B + b];
    __syncthreads();
    int lo = b * EPB, hi = min(lo + EPB, E);
    for (int e = lo + threadIdx.x; e < hi; e += 256) {
        int d = dst[e];
        unsigned rec = (unsigned)src[e] | ((unsigned)(d & 255) << 24);
        int pos = atomicAdd(&lcur[d >> NB_SHIFT], 1);
        bucketed[pos] = rec;
    }
}

// one block per bucket: derive degrees, row_ptr/row_end/dis, then fill csr_src.
__global__ void fill_csr_deg(const unsigned* __restrict__ bucketed,
                             const int* __restrict__ bstart,
                             int* __restrict__ row_ptr, int* __restrict__ row_end,
                             float* __restrict__ dis,
                             int* __restrict__ csr_src, int N) {
    __shared__ int cnt[256];
    __shared__ int rp[256];
    __shared__ int waveTot[4];
    __shared__ int waveOff[4];
    int k = blockIdx.x;
    int tid = threadIdx.x;
    int base = k << NB_SHIFT;
    cnt[tid] = 0;
    __syncthreads();
    int lo = bstart[k], hi = bstart[k + 1];
    for (int e = lo + tid; e < hi; e += 256)
        atomicAdd(&cnt[bucketed[e] >> 24], 1);
    __syncthreads();
    int v = cnt[tid];
    int lane = tid & 63, wave = tid >> 6;
    int s = v;
    #pragma unroll
    for (int o = 1; o < 64; o <<= 1) {
        int t = __shfl_up(s, o);
        if (lane >= o) s += t;
    }
    if (lane == 63) waveTot[wave] = s;
    __syncthreads();
    if (tid == 0) {
        int acc = 0;
        #pragma unroll
        for (int w = 0; w < 4; w++) { waveOff[w] = acc; acc += waveTot[w]; }
    }
    __syncthreads();
    int myrp = lo + s - v + waveOff[wave];
    rp[tid] = myrp;
    int node = base + tid;
    if (node < N) {
        row_ptr[node] = myrp;
        row_end[node] = myrp + v;
        dis[node] = rsqrtf(1.0f + (float)v);   // self-loop folded into degree
    }
    __syncthreads();
    for (int e = lo + tid; e < hi; e += 256) {
        unsigned sd = bucketed[e];
        int pos = atomicAdd(&rp[sd >> 24], 1);
        csr_src[pos] = (int)(sd & 0xFFFFFFu >> 0 & 0x00FFFFFFu);
    }
}

// ---------------- weight pack: fp32 [K][Nout] -> bf16 in MFMA FRAGMENT ORDER ----------------
// Frag order: flat = (kb*8 + t)*512 + lane*8 + j, lane = q*16 + ln,
// holding W[k = kb*32 + q*8 + j][n = t*16 + ln]. A wave's B-frag load for
// (kb, t) is one contiguous 1KB burst. Fused: W1 (K=256) then [Wmu|Wlv] (K=128).

__global__ void pack_weights(const float* __restrict__ W1, const float* __restrict__ Wmu,
                             const float* __restrict__ Wlv,
                             short* __restrict__ w1f, short* __restrict__ wcatf) {
    int i = blockIdx.x * blockDim.x + threadIdx.x;
    if (i < 128 * 256) {
        int j  = i & 7;
        int ln = (i >> 3) & 15;
        int q  = (i >> 7) & 3;
        int t  = (i >> 9) & 7;
        int kb = i >> 12;
        int n = t * 16 + ln;
        int k = kb * 32 + q * 8 + j;
        w1f[i] = f2bf(W1[k * 128 + n]);
    } else {
        int i2 = i - 128 * 256;
        if (i2 < 128 * 128) {
            int j  = i2 & 7;
            int ln = (i2 >> 3) & 15;
            int q  = (i2 >> 7) & 3;
            int t  = (i2 >> 9) & 7;
            int kb = i2 >> 12;
            int n = t * 16 + ln;
            int k = kb * 32 + q * 8 + j;
            wcatf[i2] = f2bf((n < 64) ? Wmu[k * 64 + n] : Wlv[k * 64 + (n - 64)]);
        }
    }
}

// ---------------- MFMA GEMM: C[M,128](bf16) = A[M,K] @ W (bf16 frag-order) ----------------
// Block 256 thr = 4 waves; wave w: rows blk*128 + w*32 .. +31 (two 16-row A frags).
// B frag (kb,t): contiguous 1KB burst from Bfrag. C/D: col=lane&15, row=q*4+reg (m89).
// Epilogue: scale row by dis[row], convert bf16.

template<int K, bool ABF16>
__launch_bounds__(256)
__global__ void gemm_mfma(const void* __restrict__ Ap, const short* __restrict__ Bfrag,
                          short* __restrict__ C, int M, const float* __restrict__ dis) {
    int w = threadIdx.x >> 6;
    int lane = threadIdx.x & 63;
    int ln = lane & 15;
    int q  = lane >> 4;
    int rowTile = blockIdx.x * 128 + w * 32;

    int r0 = rowTile + ln;
    int r1 = rowTile + 16 + ln;
    int r0c = (r0 < M) ? r0 : (M - 1);
    int r1c = (r1 < M) ? r1 : (M - 1);

    const float* a0F = (const float*)Ap + (size_t)r0c * K + q * 8;
    const float* a1F = (const float*)Ap + (size_t)r1c * K + q * 8;
    const short* a0B = (const short*)Ap + (size_t)r0c * K + q * 8;
    const short* a1B = (const short*)Ap + (size_t)r1c * K + q * 8;
    const short* bLane = Bfrag + lane * 8;

    floatx4 acc[2][8];
    #pragma unroll
    for (int f = 0; f < 2; f++)
        #pragma unroll
        for (int t = 0; t < 8; t++) acc[f][t] = (floatx4){0.f, 0.f, 0.f, 0.f};

    constexpr int NIT = K / 32;
    #pragma unroll
    for (int kb = 0; kb < NIT; kb++) {
        int kt = kb * 32;
        bf16x8 aF0, aF1;
        if (ABF16) {
            aF0 = *(const bf16x8*)(a0B + kt);
            aF1 = *(const bf16x8*)(a1B + kt);
        } else {
            float4 x0 = *(const float4*)(a0F + kt);
            float4 x1 = *(const float4*)(a0F + kt + 4);
            float4 y0 = *(const float4*)(a1F + kt);
            float4 y1 = *(const float4*)(a1F + kt + 4);
            aF0[0] = f2bf(x0.x); aF0[1] = f2bf(x0.y); aF0[2] = f2bf(x0.z); aF0[3] = f2bf(x0.w);
            aF0[4] = f2bf(x1.x); aF0[5] = f2bf(x1.y); aF0[6] = f2bf(x1.z); aF0[7] = f2bf(x1.w);
            aF1[0] = f2bf(y0.x); aF1[1] = f2bf(y0.y); aF1[2] = f2bf(y0.z); aF1[3] = f2bf(y0.w);
            aF1[4] = f2bf(y1.x); aF1[5] = f2bf(y1.y); aF1[6] = f2bf(y1.z); aF1[7] = f2bf(y1.w);
        }
        bf16x8 bF[8];
        #pragma unroll
        for (int t = 0; t < 8; t++)
            bF[t] = *(const bf16x8*)(bLane + (size_t)(kb * 8 + t) * 512);
        #pragma unroll
        for (int t = 0; t < 8; t++) {
            acc[0][t] = __builtin_amdgcn_mfma_f32_16x16x32_bf16(aF0, bF[t], acc[0][t], 0, 0, 0);
            acc[1][t] = __builtin_amdgcn_mfma_f32_16x16x32_bf16(aF1, bF[t], acc[1][t], 0, 0, 0);
        }
    }

    #pragma unroll
    for (int f = 0; f < 2; f++) {
        #pragma unroll
        for (int reg = 0; reg < 4; reg++) {
            int r = rowTile + f * 16 + q * 4 + reg;
            if (r < M) {
                float s = dis ? dis[r] : 1.f;
                #pragma unroll
                for (int t = 0; t < 8; t++)
                    C[(size_t)r * 128 + t * 16 + ln] = f2bf(s * acc[f][t][reg]);
            }
        }
    }
}

// ---------------- aggregation: one WAVE per node, bf16 rows, quarter-wave gathers ----------------
// zp holds pre-scaled bf16 rows z'[i] = dis[i] * (transform(x))[i]  (128 feats = 256B).
// out_node = dis[d] * ( sum_{s in N(d)} z'[s] + z'[d] ) + bias

#define AGG_BODY_BF16                                                         \
    int wave = threadIdx.x >> 6;                                              \
    int node = blockIdx.x * 4 + wave;                                         \
    if (node >= N) return;                                                    \
    int lane = threadIdx.x & 63;                                              \
    int qi = lane >> 4;                                                       \
    int fl = lane & 15;                                                       \
    int fo = fl * 8;                                                          \
    const short* zb = zp + fo;                                                \
    int start = row_ptr[node], end = row_end[node];                           \
    float acc[8];                                                             \
    _Pragma("unroll")                                                         \
    for (int j = 0; j < 8; j++) acc[j] = 0.f;                                 \
    int e = start + qi;                                                       \
    for (; e + 4 < end; e += 8) {                                             \
        int s0 = csr_src[e], s1 = csr_src[e + 4];                             \
        bf16x8 z0 = *(const bf16x8*)(zb + (size_t)s0 * 128);                  \
        bf16x8 z1 = *(const bf16x8*)(zb + (size_t)s1 * 128);                  \
        _Pragma("unroll")                                                     \
        for (int j = 0; j < 8; j++) acc[j] += bf2f(z0[j]) + bf2f(z1[j]);      \
    }                                                                         \
    for (; e < end; e += 4) {                                                 \
        int s0 = csr_src[e];                                                  \
        bf16x8 z0 = *(const bf16x8*)(zb + (size_t)s0 * 128);                  \
        _Pragma("unroll")                                                     \
        for (int j = 0; j < 8; j++) acc[j] += bf2f(z0[j]);                    \
    }                                                                         \
    if (qi == 0) {  /* self loop, added exactly once */                       \
        bf16x8 zs = *(const bf16x8*)(zb + (size_t)node * 128);                \
        _Pragma("unroll")                                                     \
        for (int j = 0; j < 8; j++) acc[j] += bf2f(zs[j]);                    \
    }                                                                         \
    _Pragma("unroll")                                                         \
    for (int j = 0; j < 8; j++) {                                             \
        acc[j] += __shfl_xor(acc[j], 16);                                     \
        acc[j] += __shfl_xor(acc[j], 32);                                     \
    }

__launch_bounds__(256)
__global__ void agg_layer1(const short* __restrict__ zp, const int* __restrict__ row_ptr,
                           const int* __restrict__ row_end, const int* __restrict__ csr_src,
                           const float* __restrict__ dis, const float* __restrict__ b1,
                           short* __restrict__ h, int N) {
    AGG_BODY_BF16
    if (qi == 0) {
        float d = dis[node];
        bf16x8 ov;
        #pragma unroll
        for (int j = 0; j < 8; j++) {
            float v = fmaf(d, acc[j], b1[fo + j]);
            v = (v > 0.f) ? v : NEG_SLOPE * v;
            ov[j] = f2bf(v);
        }
        *(bf16x8*)(h + (size_t)node * 128 + fo) = ov;
    }
}

__launch_bounds__(256)
__global__ void agg_layer2(const short* __restrict__ zp, const int* __restrict__ row_ptr,
                           const int* __restrict__ row_end, const int* __restrict__ csr_src,
                           const float* __restrict__ dis, const float* __restrict__ b_mu,
                           const float* __restrict__ b_lv, float* __restrict__ out, int N) {
    AGG_BODY_BF16
    if (qi == 0) {
        float d = dis[node];
        float r[8];
        if (fl < 8) {                        // mu: features fo..fo+7
            #pragma unroll
            for (int j = 0; j < 8; j++) r[j] = fmaf(d, acc[j], b_mu[fo + j]);
            float* p = out + (size_t)node * 64 + fo;
            *(float4*)p       = make_float4(r[0], r[1], r[2], r[3]);
            *(float4*)(p + 4) = make_float4(r[4], r[5], r[6], r[7]);
        } else {                             // logvar: features fo-64..fo-57
            #pragma unroll
            for (int j = 0; j < 8; j++) r[j] = fmaf(d, acc[j], b_lv[fo - 64 + j]);
            float* p = out + (size_t)N * 64 + (size_t)node * 64 + (fo - 64);
            *(float4*)p       = make_float4(r[0], r[1], r[2], r[3]);
            *(float4*)(p + 4) = make_float4(r[4], r[5], r[6], r[7]);
        }
    }
}

// ---------------- launcher ----------------

extern "C" void kernel_launch(void* const* d_in, const int* in_sizes, int n_in,
                              void* d_out, int out_size, void* d_ws, size_t ws_size,
                              hipStream_t stream) {
    const float* x   = (const float*)d_in[0];
    const int*   ei  = (const int*)d_in[1];    // [2,E] int32: src then dst
    const float* W1  = (const float*)d_in[2];
    const float* b1  = (const float*)d_in[3];
    const float* Wmu = (const float*)d_in[4];
    const float* bmu = (const float*)d_in[5];
    const float* Wlv = (const float*)d_in[6];
    const float* blv = (const float*)d_in[7];
    float* out = (float*)d_out;

    const int F_IN = 256;
    int N = in_sizes[0] / F_IN;   // 50000
    int E = in_sizes[1] / 2;      // 800000
    const int* e_src = ei;
    const int* e_dst = ei + E;

    char* ws = (char*)d_ws;
    size_t off = 0;
    auto carve = [&](size_t bytes) -> void* {
        void* p = ws + off;
        off += (bytes + 255) & ~(size_t)255;
        return p;
    };
    int*   row_end  = (int*)  carve((size_t)N * 4);
    int*   row_ptr  = (int*)  carve((size_t)N * 4);
    float* dis      = (float*)carve((size_t)N * 4);
    int*   csr_src  = (int*)  carve((size_t)E * 4);
    short* bufA     = (short*)carve((size_t)N * 128 * 2);  // bf16 Z1'/Z2'; aliased by `bucketed` pre-GEMM
    short* bufB     = (short*)carve((size_t)N * 128 * 2);  // bf16 h; aliased by `hist` pre-GEMM
    short* w1f      = (short*)carve(128 * 256 * 2);        // bf16 W1 frag-order
    short* wcatf    = (short*)carve(128 * 128 * 2);        // bf16 [Wmu|Wlv] frag-order
    int*   bstart   = (int*)  carve(4096);                 // bucket starts (K+1)

    // CSR-build scratch aliases the feature buffers (build fully precedes GEMMs)
    unsigned* bucketed = (unsigned*)bufA;   // E * 4B <= N*256B
    int*      hist     = (int*)bufB;        // K*B * 4B (~154 KB)

    int B = (E + EPB - 1) / EPB;            // edge blocks
    int K = (N + 255) >> NB_SHIFT;          // dst buckets

    // bucketed CSR build (degrees derived in-bucket; no node-level global scan)
    hipLaunchKernelGGL(bucket_hist, dim3(B), dim3(256), 0, stream, e_dst, E, B, K, hist);
    hipLaunchKernelGGL(bucket_starts, dim3(1), dim3(256), 0, stream, hist, B, K, E, bstart);
    hipLaunchKernelGGL(scan_hist_buckets, dim3(K), dim3(256), 0, stream, hist, bstart, B, K);
    hipLaunchKernelGGL(bucket_scatter, dim3(B), dim3(256), 0, stream, e_src, e_dst, E, B, K, hist, bucketed);
    hipLaunchKernelGGL(fill_csr_deg, dim3(K), dim3(256), 0, stream,
                       bucketed, bstart, row_ptr, row_end, dis, csr_src, N);
    // weight packs (frag order, fused)
    hipLaunchKernelGGL(pack_weights, dim3(192), dim3(256), 0, stream, W1, Wmu, Wlv, w1f, wcatf);
    // layer 1: Z1' = dis .* (x @ W1) ; h = leaky(dis .* Agg(Z1') + b1)
    hipLaunchKernelGGL((gemm_mfma<256, false>), dim3((N + 127) / 128), dim3(256), 0, stream,
                       (const void*)x, w1f, bufA, N, dis);
    hipLaunchKernelGGL(agg_layer1, dim3((N + 3) / 4), dim3(256), 0, stream,
                       bufA, row_ptr, row_end, csr_src, dis, b1, bufB, N);
    // layer 2 (mu & logvar share the aggregation): Z2' = dis .* (h @ [Wmu|Wlv])
    hipLaunchKernelGGL((gemm_mfma<128, true>), dim3((N + 127) / 128), dim3(256), 0, stream,
                       (const void*)bufB, wcatf, bufA, N, dis);
    hipLaunchKernelGGL(agg_layer2, dim3((N + 3) / 4), dim3(256), 0, stream,
                       bufA, row_ptr, row_end, csr_src, dis, bmu, blv, out, N);
}